// Round 8
// baseline (624.228 us; speedup 1.0000x reference)
//
#include <hip/hip_runtime.h>
#include <hip/hip_fp16.h>

#define NNODES 100000
#define NPAD   100032            // 64*1563
#define NEDGES 1600000
#define NBLK_GEMM (NPAD / 64)    // 1563

#define BKT   512                // nodes per bucket
#define NBKT  ((NNODES + BKT - 1) / BKT)   // 196
#define CAP   10240              // slab capacity (mean 8192, 22 sigma slack)
#define EPB   2048               // edges per block, pass A (782 blocks)
#define NBLK_A ((NEDGES + EPB - 1) / EPB)

typedef _Float16 half8 __attribute__((ext_vector_type(8)));
typedef float floatx4 __attribute__((ext_vector_type(4)));

// ---------------- CSR build: two-level bucket sort (verbatim) ----------------

__global__ __launch_bounds__(256) void k_binA(const int* __restrict__ src, const int* __restrict__ dst,
                                              int* __restrict__ gcur, unsigned* __restrict__ pairs) {
    __shared__ int cnt[NBKT];
    __shared__ int cur[NBKT];
    int t = threadIdx.x;
    if (t < NBKT) cnt[t] = 0;
    __syncthreads();
    int e0 = blockIdx.x * EPB;
    for (int i = t; i < EPB; i += 256) {
        int e = e0 + i;
        if (e < NEDGES) atomicAdd(&cnt[dst[e] >> 9], 1);
    }
    __syncthreads();
    if (t < NBKT) {
        int c = cnt[t];
        cur[t] = (c > 0) ? atomicAdd(&gcur[t], c) : 0;
    }
    __syncthreads();
    for (int i = t; i < EPB; i += 256) {
        int e = e0 + i;
        if (e < NEDGES) {
            int d = dst[e];
            int b = d >> 9;
            int pos = atomicAdd(&cur[b], 1);
            pairs[b * CAP + pos] = (unsigned)src[e] | ((unsigned)(d & 511) << 20);
        }
    }
}

__global__ __launch_bounds__(256) void k_bktscan(const int* __restrict__ gcur, int* __restrict__ bkt_base,
                                                 int* __restrict__ row_ptr) {
    __shared__ int lds[256];
    int t = threadIdx.x;
    int v = (t < NBKT) ? gcur[t] : 0;
    lds[t] = v;
    __syncthreads();
#pragma unroll
    for (int off = 1; off < 256; off <<= 1) {
        int u = (t >= off) ? lds[t - off] : 0;
        __syncthreads();
        lds[t] += u;
        __syncthreads();
    }
    if (t < NBKT) bkt_base[t] = lds[t] - v;
    if (t == 0) row_ptr[NNODES] = NEDGES;
}

__global__ __launch_bounds__(512) void k_binB(const unsigned* __restrict__ pairs, const int* __restrict__ gcnt,
                                              const int* __restrict__ bkt_base,
                                              int* __restrict__ row_ptr, float* __restrict__ deg_inv,
                                              int* __restrict__ edge_src) {
    __shared__ int hist[BKT];
    __shared__ int sc[BKT];
    int b = blockIdx.x;
    int t = threadIdx.x;
    int n = gcnt[b];
    int base = bkt_base[b];
    const unsigned* pp = pairs + (size_t)b * CAP;
    hist[t] = 0;
    __syncthreads();
    for (int i = t; i < n; i += 512) atomicAdd(&hist[pp[i] >> 20], 1);
    __syncthreads();
    int v = hist[t];
    sc[t] = v;
    __syncthreads();
#pragma unroll
    for (int off = 1; off < 512; off <<= 1) {
        int u = (t >= off) ? sc[t - off] : 0;
        __syncthreads();
        sc[t] += u;
        __syncthreads();
    }
    int pref = sc[t] - v;
    int node = b * BKT + t;
    if (node < NNODES) {
        row_ptr[node] = base + pref;
        deg_inv[node] = 1.0f / fmaxf((float)v, 1.0f);
    }
    __syncthreads();
    hist[t] = pref;
    __syncthreads();
    for (int i = t; i < n; i += 512) {
        unsigned p = pp[i];
        int pos = atomicAdd(&hist[p >> 20], 1);
        edge_src[base + pos] = (int)(p & 0xFFFFF);
    }
}

// ---------------- fused prep: f2h + 3x wshuf (verbatim) ----------------------
template <int C>
__device__ inline void wshuf_one(const float* __restrict__ Ws, const float* __restrict__ Wn,
                                 __half* __restrict__ Wb, int t) {
    constexpr int NCT = 2 * C / 16;
    int lane  = t & 63;
    int ctile = (t >> 6) % NCT;
    int kstep = t / (64 * NCT);
    int n  = ctile * 16 + (lane & 15);
    int k0 = kstep * 32 + (lane >> 4) * 8;
    half8 w8;
#pragma unroll
    for (int j = 0; j < 8; ++j) {
        int k = k0 + j;
        float w = (n < C) ? Ws[k * C + n] : Wn[k * C + (n - C)];
        w8[j] = (_Float16)w;
    }
    ((half8*)Wb)[t] = w8;
}

#define F2H_BLK 12500   // NNODES*128 floats = 3.2M float4 / 256

__global__ __launch_bounds__(256) void k_prep(const float* __restrict__ x, __half* __restrict__ x16,
                                              const float* __restrict__ Ws0, const float* __restrict__ Wn0, __half* __restrict__ Wb0,
                                              const float* __restrict__ Ws1, const float* __restrict__ Wn1, __half* __restrict__ Wb1,
                                              const float* __restrict__ Ws2, const float* __restrict__ Wn2, __half* __restrict__ Wb2) {
    int blk = blockIdx.x;
    if (blk < F2H_BLK) {
        int i = blk * 256 + threadIdx.x;
        float4 v = ((const float4*)x)[i];
        __half2* o = (__half2*)(x16 + (size_t)i * 4);
        o[0] = __floats2half2_rn(v.x, v.y);
        o[1] = __floats2half2_rn(v.z, v.w);
    } else if (blk < F2H_BLK + 16) {
        wshuf_one<128>(Ws0, Wn0, Wb0, (blk - F2H_BLK) * 256 + threadIdx.x);
    } else if (blk < F2H_BLK + 32) {
        wshuf_one<128>(Ws1, Wn1, Wb1, (blk - F2H_BLK - 16) * 256 + threadIdx.x);
    } else {
        wshuf_one<64>(Ws2, Wn2, Wb2, (blk - F2H_BLK - 32) * 256 + threadIdx.x);
    }
}

// ---------------- MFMA GEMM (verbatim R4/R6): zs = h@Ws+b, zn = h@Wn ---------
template <int C, bool ZS32>
__global__ __launch_bounds__(256) void k_gemm2(const __half* __restrict__ A,
                                               const __half* __restrict__ Wb,
                                               const float* __restrict__ bias,
                                               void* __restrict__ zs,
                                               __half* __restrict__ zn) {
    constexpr int NCT = 2 * C / 16;
    int lane = threadIdx.x & 63;
    int wave = threadIdx.x >> 6;
    int row0 = blockIdx.x * 64 + wave * 16;
    int m = lane & 15, quad = lane >> 4;
    const half8* Aq = (const half8*)(A + (size_t)(row0 + m) * 128 + quad * 8);
    const half8* Bq = (const half8*)Wb;

    floatx4 acc[NCT];
#pragma unroll
    for (int c = 0; c < NCT; ++c) acc[c] = floatx4{0.f, 0.f, 0.f, 0.f};

#pragma unroll
    for (int ks = 0; ks < 4; ++ks) {
        half8 a = Aq[ks * 4];
#pragma unroll
        for (int c = 0; c < NCT; ++c) {
            half8 b = Bq[(size_t)(ks * NCT + c) * 64 + lane];
            acc[c] = __builtin_amdgcn_mfma_f32_16x16x32_f16(a, b, acc[c], 0, 0, 0);
        }
    }

#pragma unroll
    for (int c = 0; c < NCT; ++c) {
        bool is_self = (c < NCT / 2);
        int col = (is_self ? c : c - NCT / 2) * 16 + m;
        float bv = is_self ? bias[col] : 0.f;
#pragma unroll
        for (int r = 0; r < 4; ++r) {
            int row = row0 + quad * 4 + r;
            if (row < NNODES) {
                float v = acc[c][r] + bv;
                if (is_self) {
                    if (ZS32) ((float*)zs)[(size_t)row * C + col] = v;
                    else      ((__half*)zs)[(size_t)row * C + col] = __float2half(v);
                } else {
                    zn[(size_t)row * C + col] = __float2half(v);
                }
            }
        }
    }
}

// ---------------- FUSED: h = relu(zs + deg_inv*sum zn[src]) -> GEMM ----------
// Phase 1 (R6 aggadd C=128 math): 4 waves x 16 nodes sequential, h rows to LDS.
// Phase 2 (R4 gemm2 math): A-fragments from LDS, outputs zs_out/zn_out.
template <int COUT, bool ZS32>
__global__ __launch_bounds__(256) void k_fused(const __half* __restrict__ zn_in,
                                               const __half* __restrict__ zs_in,
                                               const int* __restrict__ row_ptr,
                                               const int* __restrict__ edge_src,
                                               const float* __restrict__ deg_inv,
                                               const __half* __restrict__ Wb,
                                               const float* __restrict__ bias,
                                               void* __restrict__ zs_out,
                                               __half* __restrict__ zn_out) {
    constexpr int NCT = 2 * COUT / 16;
    __shared__ __half hl[64][136];            // 136: +8 pad keeps 16B alignment
    int lane = threadIdx.x & 63;
    int wave = threadIdx.x >> 6;
    int row0 = blockIdx.x * 64;
    int su = lane >> 4;                       // 4 subgroups of 16 lanes
    int lr = lane & 15;                       // half8 slot within row
    const half8* zb = (const half8*)zn_in;

    // ---- phase 1: aggregate 16 nodes per wave ----
    for (int i = 0; i < 16; ++i) {
        int node = row0 + wave * 16 + i;
        int beg = 0, end = 0;
        float di = 0.f;
        if (node < NNODES) { beg = row_ptr[node]; end = row_ptr[node + 1]; di = deg_inv[node]; }
        float a[4][8];
#pragma unroll
        for (int u = 0; u < 4; ++u)
#pragma unroll
            for (int j = 0; j < 8; ++j) a[u][j] = 0.f;
        int p = beg + su;
        for (; p + 12 < end; p += 16) {
            half8 v[4];
#pragma unroll
            for (int u = 0; u < 4; ++u) v[u] = zb[(size_t)edge_src[p + u * 4] * 16 + lr];
#pragma unroll
            for (int u = 0; u < 4; ++u)
#pragma unroll
                for (int j = 0; j < 8; ++j) a[u][j] = fmaf((float)v[u][j], 1.0f, a[u][j]);
        }
        for (; p < end; p += 4) {
            half8 v = zb[(size_t)edge_src[p] * 16 + lr];
#pragma unroll
            for (int j = 0; j < 8; ++j) a[0][j] = fmaf((float)v[j], 1.0f, a[0][j]);
        }
        float s[8];
#pragma unroll
        for (int j = 0; j < 8; ++j) s[j] = (a[0][j] + a[1][j]) + (a[2][j] + a[3][j]);
#pragma unroll
        for (int off = 32; off >= 16; off >>= 1) {
#pragma unroll
            for (int j = 0; j < 8; ++j) s[j] += __shfl_xor(s[j], off, 64);
        }
        if (su == 0) {
            half8 o;
            if (node < NNODES) {
                half8 z = ((const half8*)zs_in)[(size_t)node * 16 + lr];
#pragma unroll
                for (int j = 0; j < 8; ++j) {
                    float t = (float)z[j] + s[j] * di;
                    o[j] = (_Float16)fmaxf(t, 0.f);
                }
            } else {
#pragma unroll
                for (int j = 0; j < 8; ++j) o[j] = (_Float16)0;
            }
            *(half8*)&hl[wave * 16 + i][lr * 8] = o;
        }
    }
    __syncthreads();

    // ---- phase 2: GEMM from LDS tile ----
    int m = lane & 15, quad = lane >> 4;
    const half8* Bq = (const half8*)Wb;
    floatx4 acc[NCT];
#pragma unroll
    for (int c = 0; c < NCT; ++c) acc[c] = floatx4{0.f, 0.f, 0.f, 0.f};

#pragma unroll
    for (int ks = 0; ks < 4; ++ks) {
        half8 a = *(const half8*)&hl[wave * 16 + m][quad * 8 + ks * 32];
#pragma unroll
        for (int c = 0; c < NCT; ++c) {
            half8 b = Bq[(size_t)(ks * NCT + c) * 64 + lane];
            acc[c] = __builtin_amdgcn_mfma_f32_16x16x32_f16(a, b, acc[c], 0, 0, 0);
        }
    }

#pragma unroll
    for (int c = 0; c < NCT; ++c) {
        bool is_self = (c < NCT / 2);
        int col = (is_self ? c : c - NCT / 2) * 16 + m;
        float bv = is_self ? bias[col] : 0.f;
#pragma unroll
        for (int r = 0; r < 4; ++r) {
            int row = row0 + wave * 16 + quad * 4 + r;
            if (row < NNODES) {
                float v = acc[c][r] + bv;
                if (is_self) {
                    if (ZS32) ((float*)zs_out)[(size_t)row * COUT + col] = v;
                    else      ((__half*)zs_out)[(size_t)row * COUT + col] = __float2half(v);
                } else {
                    zn_out[(size_t)row * COUT + col] = __float2half(v);
                }
            }
        }
    }
}

// ---------------- final gather-add (verbatim R6, C=64 path) ------------------
template <int C, bool RELU, bool ZS32>
__global__ __launch_bounds__(256) void k_aggadd(const __half* __restrict__ zn,
                                                const void* __restrict__ zs,
                                                const int* __restrict__ row_ptr,
                                                const int* __restrict__ edge_src,
                                                const float* __restrict__ deg_inv,
                                                void* __restrict__ outv) {
    constexpr int LPR  = C / 8;
    constexpr int NSUB = 64 / LPR;
    constexpr int UNR  = (C == 128) ? 4 : 2;
    int node = blockIdx.x * 4 + (threadIdx.x >> 6);
    int lane = threadIdx.x & 63;
    int su = lane / LPR;
    int lr = lane % LPR;
    int beg = row_ptr[node];
    int end = row_ptr[node + 1];
    const half8* zb = (const half8*)zn;
    float a[UNR][8];
#pragma unroll
    for (int u = 0; u < UNR; ++u)
#pragma unroll
        for (int j = 0; j < 8; ++j) a[u][j] = 0.f;

    int p = beg + su;
    for (; p + NSUB * (UNR - 1) < end; p += NSUB * UNR) {
        half8 v[UNR];
#pragma unroll
        for (int u = 0; u < UNR; ++u) v[u] = zb[(size_t)edge_src[p + u * NSUB] * LPR + lr];
#pragma unroll
        for (int u = 0; u < UNR; ++u)
#pragma unroll
            for (int j = 0; j < 8; ++j) a[u][j] = fmaf((float)v[u][j], 1.0f, a[u][j]);
    }
    for (; p < end; p += NSUB) {
        half8 v = zb[(size_t)edge_src[p] * LPR + lr];
#pragma unroll
        for (int j = 0; j < 8; ++j) a[0][j] = fmaf((float)v[j], 1.0f, a[0][j]);
    }

    float s[8];
#pragma unroll
    for (int j = 0; j < 8; ++j) {
        s[j] = a[0][j];
#pragma unroll
        for (int u = 1; u < UNR; ++u) s[j] += a[u][j];
    }
#pragma unroll
    for (int off = 32; off >= LPR; off >>= 1) {
#pragma unroll
        for (int j = 0; j < 8; ++j) s[j] += __shfl_xor(s[j], off, 64);
    }

    if (su == 0) {
        float di = deg_inv[node];
        float o[8];
        if (ZS32) {
            const float4* zp = (const float4*)zs + (size_t)node * (C / 4) + lr * 2;
            float4 z0 = zp[0], z1 = zp[1];
            o[0] = z0.x + s[0] * di; o[1] = z0.y + s[1] * di;
            o[2] = z0.z + s[2] * di; o[3] = z0.w + s[3] * di;
            o[4] = z1.x + s[4] * di; o[5] = z1.y + s[5] * di;
            o[6] = z1.z + s[6] * di; o[7] = z1.w + s[7] * di;
        } else {
            half8 z = ((const half8*)zs)[(size_t)node * LPR + lr];
#pragma unroll
            for (int j = 0; j < 8; ++j) o[j] = (float)z[j] + s[j] * di;
        }
        if (RELU) {
#pragma unroll
            for (int j = 0; j < 8; ++j) o[j] = fmaxf(o[j], 0.f);
        }
        if (ZS32) {
            float4* op = (float4*)outv + (size_t)node * (C / 4) + lr * 2;
            op[0] = float4{o[0], o[1], o[2], o[3]};
            op[1] = float4{o[4], o[5], o[6], o[7]};
        } else {
            half8 h;
#pragma unroll
            for (int j = 0; j < 8; ++j) h[j] = (_Float16)o[j];
            ((half8*)outv)[(size_t)node * LPR + lr] = h;
        }
    }
}

// ---------------- launch ----------------

extern "C" void kernel_launch(void* const* d_in, const int* in_sizes, int n_in,
                              void* d_out, int out_size, void* d_ws, size_t ws_size,
                              hipStream_t stream) {
    const float* x   = (const float*)d_in[0];
    const int*   src = (const int*)d_in[1];
    const int*   dst = (const int*)d_in[2];
    const float* Ws0 = (const float*)d_in[3];
    const float* Wn0 = (const float*)d_in[4];
    const float* b0  = (const float*)d_in[5];
    const float* Ws1 = (const float*)d_in[6];
    const float* Wn1 = (const float*)d_in[7];
    const float* b1  = (const float*)d_in[8];
    const float* Ws2 = (const float*)d_in[9];
    const float* Wn2 = (const float*)d_in[10];
    const float* b2  = (const float*)d_in[11];
    float* out = (float*)d_out;

    char* ws = (char*)d_ws;
    size_t off = 0;
    auto alloc = [&](size_t bytes) -> void* {
        off = (off + 255) & ~(size_t)255;
        void* p = ws + off;
        off += bytes;
        return p;
    };
    int*      row_ptr  = (int*)alloc((size_t)(NNODES + 1) * 4);
    float*    deg_inv  = (float*)alloc((size_t)NNODES * 4);
    int*      edge_src = (int*)alloc((size_t)NEDGES * 4);
    int*      gcur     = (int*)alloc((size_t)NBKT * 4);
    int*      bkt_base = (int*)alloc((size_t)(NBKT + 1) * 4);
    unsigned* pairs    = (unsigned*)alloc((size_t)NBKT * CAP * 4);
    __half*   x16      = (__half*)alloc((size_t)NPAD * 128 * 2);
    __half*   zsA      = (__half*)alloc((size_t)NNODES * 128 * 2);
    __half*   znA      = (__half*)alloc((size_t)NNODES * 128 * 2);
    __half*   zsB      = (__half*)alloc((size_t)NNODES * 128 * 2);
    __half*   znB      = (__half*)alloc((size_t)NNODES * 128 * 2);
    float*    zs32     = (float*)alloc((size_t)NNODES * 64 * 4);
    __half*   zn64     = (__half*)alloc((size_t)NNODES * 64 * 2);
    __half*   Wb0      = (__half*)alloc((size_t)4 * 16 * 64 * 8 * 2);
    __half*   Wb1      = (__half*)alloc((size_t)4 * 16 * 64 * 8 * 2);
    __half*   Wb2      = (__half*)alloc((size_t)4 * 8 * 64 * 8 * 2);
    (void)ws_size; (void)n_in; (void)in_sizes; (void)out_size;

    // CSR build (bucketed)
    hipMemsetAsync(gcur, 0, (size_t)NBKT * 4, stream);
    k_binA<<<NBLK_A, 256, 0, stream>>>(src, dst, gcur, pairs);
    k_bktscan<<<1, 256, 0, stream>>>(gcur, bkt_base, row_ptr);
    k_binB<<<NBKT, 512, 0, stream>>>(pairs, gcur, bkt_base, row_ptr, deg_inv, edge_src);

    // prep: f2h + 3x wshuf fused
    k_prep<<<F2H_BLK + 40, 256, 0, stream>>>(x, x16, Ws0, Wn0, Wb0, Ws1, Wn1, Wb1, Ws2, Wn2, Wb2);

    // layer 0 GEMM: x16 -> zs0, zn0
    k_gemm2<128, false><<<NBLK_GEMM, 256, 0, stream>>>(x16, Wb0, b0, zsA, znA);
    // fused: h1 = relu(zs0 + agg zn0); zs1 = h1@Ws1+b1, zn1 = h1@Wn1
    k_fused<128, false><<<NBLK_GEMM, 256, 0, stream>>>(znA, zsA, row_ptr, edge_src, deg_inv, Wb1, b1, zsB, znB);
    // fused: h2 = relu(zs1 + agg zn1); zs2 = h2@Ws2+b2 (fp32), zn2 = h2@Wn2
    k_fused<64, true><<<NBLK_GEMM, 256, 0, stream>>>(znB, zsB, row_ptr, edge_src, deg_inv, Wb2, b2, zs32, zn64);
    // final: out = zs2 + deg_inv * agg zn2
    k_aggadd<64, false, true><<<NNODES / 4, 256, 0, stream>>>(zn64, zs32, row_ptr, edge_src, deg_inv, out);
}

// Round 9
// 481.846 us; speedup vs baseline: 1.2955x; 1.2955x over previous
//
#include <hip/hip_runtime.h>
#include <hip/hip_fp16.h>

#define NNODES 100000
#define NPAD   100096            // 128*782, padded so GEMM A-loads need no mask
#define NEDGES 1600000
#define NBLK_GEMM (NPAD / 128)   // 782 (32 rows/wave x 4 waves)

#define BKT   512                // nodes per bucket
#define NBKT  ((NNODES + BKT - 1) / BKT)   // 196
#define CAP   10240              // slab capacity (mean 8192, 22 sigma slack)
#define EPB   2048               // edges per block, pass A (782 blocks)
#define NBLK_A ((NEDGES + EPB - 1) / EPB)

typedef _Float16 half8 __attribute__((ext_vector_type(8)));
typedef float floatx4 __attribute__((ext_vector_type(4)));

// ---------------- W pre-shuffle helper (verbatim R6) -------------------------
template <int C>
__device__ inline void wshuf_one(const float* __restrict__ Ws, const float* __restrict__ Wn,
                                 __half* __restrict__ Wb, int t) {
    constexpr int NCT = 2 * C / 16;
    int lane  = t & 63;
    int ctile = (t >> 6) % NCT;
    int kstep = t / (64 * NCT);
    int n  = ctile * 16 + (lane & 15);
    int k0 = kstep * 32 + (lane >> 4) * 8;
    half8 w8;
#pragma unroll
    for (int j = 0; j < 8; ++j) {
        int k = k0 + j;
        float w = (n < C) ? Ws[k * C + n] : Wn[k * C + (n - C)];
        w8[j] = (_Float16)w;
    }
    ((half8*)Wb)[t] = w8;
}

#define F2H_BLK 12500   // NNODES*128 floats = 3.2M float4 / 256

// ---------------- CSR pass A + prep (f2h + wshuf), merged --------------------
__global__ __launch_bounds__(256) void k_binA_prep(
        const int* __restrict__ src, const int* __restrict__ dst,
        int* __restrict__ gcur, unsigned* __restrict__ pairs,
        const float* __restrict__ x, __half* __restrict__ x16,
        const float* __restrict__ Ws0, const float* __restrict__ Wn0, __half* __restrict__ Wb0,
        const float* __restrict__ Ws1, const float* __restrict__ Wn1, __half* __restrict__ Wb1,
        const float* __restrict__ Ws2, const float* __restrict__ Wn2, __half* __restrict__ Wb2) {
    int blk = blockIdx.x;
    if (blk >= NBLK_A) {
        int b2 = blk - NBLK_A;
        if (b2 < F2H_BLK) {
            int i = b2 * 256 + threadIdx.x;
            float4 v = ((const float4*)x)[i];
            __half2* o = (__half2*)(x16 + (size_t)i * 4);
            o[0] = __floats2half2_rn(v.x, v.y);
            o[1] = __floats2half2_rn(v.z, v.w);
        } else if (b2 < F2H_BLK + 16) {
            wshuf_one<128>(Ws0, Wn0, Wb0, (b2 - F2H_BLK) * 256 + threadIdx.x);
        } else if (b2 < F2H_BLK + 32) {
            wshuf_one<128>(Ws1, Wn1, Wb1, (b2 - F2H_BLK - 16) * 256 + threadIdx.x);
        } else {
            wshuf_one<64>(Ws2, Wn2, Wb2, (b2 - F2H_BLK - 32) * 256 + threadIdx.x);
        }
        return;
    }
    // ---- binA path (verbatim R6) ----
    __shared__ int cnt[NBKT];
    __shared__ int cur[NBKT];
    int t = threadIdx.x;
    if (t < NBKT) cnt[t] = 0;
    __syncthreads();
    int e0 = blk * EPB;
    for (int i = t; i < EPB; i += 256) {
        int e = e0 + i;
        if (e < NEDGES) atomicAdd(&cnt[dst[e] >> 9], 1);
    }
    __syncthreads();
    if (t < NBKT) {
        int c = cnt[t];
        cur[t] = (c > 0) ? atomicAdd(&gcur[t], c) : 0;
    }
    __syncthreads();
    for (int i = t; i < EPB; i += 256) {
        int e = e0 + i;
        if (e < NEDGES) {
            int d = dst[e];
            int b = d >> 9;
            int pos = atomicAdd(&cur[b], 1);
            pairs[b * CAP + pos] = (unsigned)src[e] | ((unsigned)(d & 511) << 20);
        }
    }
}

// ---------------- CSR pass B, with in-block bucket-base scan -----------------
__global__ __launch_bounds__(512) void k_binB(const unsigned* __restrict__ pairs,
                                              const int* __restrict__ gcur,
                                              int* __restrict__ row_ptr, float* __restrict__ deg_inv,
                                              int* __restrict__ edge_src) {
    __shared__ int hist[BKT];
    __shared__ int sc[BKT];
    int b = blockIdx.x;
    int t = threadIdx.x;
    int n = gcur[b];
    const unsigned* pp = pairs + (size_t)b * CAP;
    // bucket-base: inclusive scan of all 196 bucket counts (tiny)
    int gv = (t < NBKT) ? gcur[t] : 0;
    sc[t] = gv;
    hist[t] = 0;
    __syncthreads();
#pragma unroll
    for (int off = 1; off < 512; off <<= 1) {
        int u = (t >= off) ? sc[t - off] : 0;
        __syncthreads();
        sc[t] += u;
        __syncthreads();
    }
    int base = sc[b] - n;            // exclusive prefix of this bucket
    if (b == 0 && t == 0) row_ptr[NNODES] = NEDGES;
    // local histogram of 512 nodes
    for (int i = t; i < n; i += 512) atomicAdd(&hist[pp[i] >> 20], 1);
    __syncthreads();
    int v = hist[t];
    sc[t] = v;
    __syncthreads();
#pragma unroll
    for (int off = 1; off < 512; off <<= 1) {
        int u = (t >= off) ? sc[t - off] : 0;
        __syncthreads();
        sc[t] += u;
        __syncthreads();
    }
    int pref = sc[t] - v;
    int node = b * BKT + t;
    if (node < NNODES) {
        row_ptr[node] = base + pref;
        deg_inv[node] = 1.0f / fmaxf((float)v, 1.0f);
    }
    __syncthreads();
    hist[t] = pref;
    __syncthreads();
    for (int i = t; i < n; i += 512) {
        unsigned p = pp[i];
        int pos = atomicAdd(&hist[p >> 20], 1);
        edge_src[base + pos] = (int)(p & 0xFFFFF);
    }
}

// ---------------- MFMA GEMM, 32 rows/wave (B-frag reused 2x) -----------------
// zs = h@Ws + b, zn = h@Wn ; K=128 in 4 steps; wave covers rows [row0,row0+32).
template <int C, bool ZS32>
__global__ __launch_bounds__(256) void k_gemm2(const __half* __restrict__ A,
                                               const __half* __restrict__ Wb,
                                               const float* __restrict__ bias,
                                               void* __restrict__ zs,
                                               __half* __restrict__ zn) {
    constexpr int NCT = 2 * C / 16;
    int lane = threadIdx.x & 63;
    int wave = threadIdx.x >> 6;
    int row0 = blockIdx.x * 128 + wave * 32;
    int m = lane & 15, quad = lane >> 4;
    const half8* Aq0 = (const half8*)(A + (size_t)(row0 + m) * 128 + quad * 8);
    const half8* Aq1 = (const half8*)(A + (size_t)(row0 + 16 + m) * 128 + quad * 8);
    const half8* Bq = (const half8*)Wb;

    floatx4 acc0[NCT], acc1[NCT];
#pragma unroll
    for (int c = 0; c < NCT; ++c) {
        acc0[c] = floatx4{0.f, 0.f, 0.f, 0.f};
        acc1[c] = floatx4{0.f, 0.f, 0.f, 0.f};
    }

#pragma unroll
    for (int ks = 0; ks < 4; ++ks) {
        half8 a0 = Aq0[ks * 4];
        half8 a1 = Aq1[ks * 4];
#pragma unroll
        for (int c = 0; c < NCT; ++c) {
            half8 b = Bq[(size_t)(ks * NCT + c) * 64 + lane];
            acc0[c] = __builtin_amdgcn_mfma_f32_16x16x32_f16(a0, b, acc0[c], 0, 0, 0);
            acc1[c] = __builtin_amdgcn_mfma_f32_16x16x32_f16(a1, b, acc1[c], 0, 0, 0);
        }
    }

#pragma unroll
    for (int g = 0; g < 2; ++g) {
#pragma unroll
        for (int c = 0; c < NCT; ++c) {
            bool is_self = (c < NCT / 2);
            int col = (is_self ? c : c - NCT / 2) * 16 + m;
            float bv = is_self ? bias[col] : 0.f;
            const floatx4& acc = g ? acc1[c] : acc0[c];
#pragma unroll
            for (int r = 0; r < 4; ++r) {
                int row = row0 + g * 16 + quad * 4 + r;
                if (row < NNODES) {
                    float v = acc[r] + bv;
                    if (is_self) {
                        if (ZS32) ((float*)zs)[(size_t)row * C + col] = v;
                        else      ((__half*)zs)[(size_t)row * C + col] = __float2half(v);
                    } else {
                        zn[(size_t)row * C + col] = __float2half(v);
                    }
                }
            }
        }
    }
}

// ---------------- gather-add (verbatim R6): out = [relu](zs + di*sum zn[src])
template <int C, bool RELU, bool ZS32>
__global__ __launch_bounds__(256) void k_aggadd(const __half* __restrict__ zn,
                                                const void* __restrict__ zs,
                                                const int* __restrict__ row_ptr,
                                                const int* __restrict__ edge_src,
                                                const float* __restrict__ deg_inv,
                                                void* __restrict__ outv) {
    constexpr int LPR  = C / 8;
    constexpr int NSUB = 64 / LPR;
    constexpr int UNR  = (C == 128) ? 4 : 2;
    int node = blockIdx.x * 4 + (threadIdx.x >> 6);
    int lane = threadIdx.x & 63;
    int su = lane / LPR;
    int lr = lane % LPR;
    int beg = row_ptr[node];
    int end = row_ptr[node + 1];
    const half8* zb = (const half8*)zn;
    float a[UNR][8];
#pragma unroll
    for (int u = 0; u < UNR; ++u)
#pragma unroll
        for (int j = 0; j < 8; ++j) a[u][j] = 0.f;

    int p = beg + su;
    for (; p + NSUB * (UNR - 1) < end; p += NSUB * UNR) {
        half8 v[UNR];
#pragma unroll
        for (int u = 0; u < UNR; ++u) v[u] = zb[(size_t)edge_src[p + u * NSUB] * LPR + lr];
#pragma unroll
        for (int u = 0; u < UNR; ++u)
#pragma unroll
            for (int j = 0; j < 8; ++j) a[u][j] = fmaf((float)v[u][j], 1.0f, a[u][j]);
    }
    for (; p < end; p += NSUB) {
        half8 v = zb[(size_t)edge_src[p] * LPR + lr];
#pragma unroll
        for (int j = 0; j < 8; ++j) a[0][j] = fmaf((float)v[j], 1.0f, a[0][j]);
    }

    float s[8];
#pragma unroll
    for (int j = 0; j < 8; ++j) {
        s[j] = a[0][j];
#pragma unroll
        for (int u = 1; u < UNR; ++u) s[j] += a[u][j];
    }
#pragma unroll
    for (int off = 32; off >= LPR; off >>= 1) {
#pragma unroll
        for (int j = 0; j < 8; ++j) s[j] += __shfl_xor(s[j], off, 64);
    }

    if (su == 0) {
        float di = deg_inv[node];
        float o[8];
        if (ZS32) {
            const float4* zp = (const float4*)zs + (size_t)node * (C / 4) + lr * 2;
            float4 z0 = zp[0], z1 = zp[1];
            o[0] = z0.x + s[0] * di; o[1] = z0.y + s[1] * di;
            o[2] = z0.z + s[2] * di; o[3] = z0.w + s[3] * di;
            o[4] = z1.x + s[4] * di; o[5] = z1.y + s[5] * di;
            o[6] = z1.z + s[6] * di; o[7] = z1.w + s[7] * di;
        } else {
            half8 z = ((const half8*)zs)[(size_t)node * LPR + lr];
#pragma unroll
            for (int j = 0; j < 8; ++j) o[j] = (float)z[j] + s[j] * di;
        }
        if (RELU) {
#pragma unroll
            for (int j = 0; j < 8; ++j) o[j] = fmaxf(o[j], 0.f);
        }
        if (ZS32) {
            float4* op = (float4*)outv + (size_t)node * (C / 4) + lr * 2;
            op[0] = float4{o[0], o[1], o[2], o[3]};
            op[1] = float4{o[4], o[5], o[6], o[7]};
        } else {
            half8 h;
#pragma unroll
            for (int j = 0; j < 8; ++j) h[j] = (_Float16)o[j];
            ((half8*)outv)[(size_t)node * LPR + lr] = h;
        }
    }
}

// ---------------- launch ----------------

extern "C" void kernel_launch(void* const* d_in, const int* in_sizes, int n_in,
                              void* d_out, int out_size, void* d_ws, size_t ws_size,
                              hipStream_t stream) {
    const float* x   = (const float*)d_in[0];
    const int*   src = (const int*)d_in[1];
    const int*   dst = (const int*)d_in[2];
    const float* Ws0 = (const float*)d_in[3];
    const float* Wn0 = (const float*)d_in[4];
    const float* b0  = (const float*)d_in[5];
    const float* Ws1 = (const float*)d_in[6];
    const float* Wn1 = (const float*)d_in[7];
    const float* b1  = (const float*)d_in[8];
    const float* Ws2 = (const float*)d_in[9];
    const float* Wn2 = (const float*)d_in[10];
    const float* b2  = (const float*)d_in[11];
    float* out = (float*)d_out;

    char* ws = (char*)d_ws;
    size_t off = 0;
    auto alloc = [&](size_t bytes) -> void* {
        off = (off + 255) & ~(size_t)255;
        void* p = ws + off;
        off += bytes;
        return p;
    };
    int*      row_ptr  = (int*)alloc((size_t)(NNODES + 1) * 4);
    float*    deg_inv  = (float*)alloc((size_t)NNODES * 4);
    int*      edge_src = (int*)alloc((size_t)NEDGES * 4);
    int*      gcur     = (int*)alloc((size_t)NBKT * 4);
    unsigned* pairs    = (unsigned*)alloc((size_t)NBKT * CAP * 4);
    __half*   x16      = (__half*)alloc((size_t)NPAD * 128 * 2);
    __half*   h1       = (__half*)alloc((size_t)NPAD * 128 * 2);
    __half*   h2       = (__half*)alloc((size_t)NPAD * 128 * 2);
    __half*   zs16     = (__half*)alloc((size_t)NNODES * 128 * 2);
    __half*   zn128    = (__half*)alloc((size_t)NNODES * 128 * 2);
    float*    zs32     = (float*)alloc((size_t)NNODES * 64 * 4);
    __half*   zn64     = (__half*)alloc((size_t)NNODES * 64 * 2);
    __half*   Wb0      = (__half*)alloc((size_t)4 * 16 * 64 * 8 * 2);
    __half*   Wb1      = (__half*)alloc((size_t)4 * 16 * 64 * 8 * 2);
    __half*   Wb2      = (__half*)alloc((size_t)4 * 8 * 64 * 8 * 2);
    (void)ws_size; (void)n_in; (void)in_sizes; (void)out_size;

    // CSR pass A + prep (concurrent), then pass B (self-scanning)
    hipMemsetAsync(gcur, 0, (size_t)NBKT * 4, stream);
    k_binA_prep<<<NBLK_A + F2H_BLK + 40, 256, 0, stream>>>(
        src, dst, gcur, pairs, x, x16, Ws0, Wn0, Wb0, Ws1, Wn1, Wb1, Ws2, Wn2, Wb2);
    k_binB<<<NBKT, 512, 0, stream>>>(pairs, gcur, row_ptr, deg_inv, edge_src);

    // layer 0: x16 -> h1
    k_gemm2<128, false><<<NBLK_GEMM, 256, 0, stream>>>(x16, Wb0, b0, zs16, zn128);
    k_aggadd<128, true, false><<<NNODES / 4, 256, 0, stream>>>(zn128, zs16, row_ptr, edge_src, deg_inv, h1);
    // layer 1: h1 -> h2
    k_gemm2<128, false><<<NBLK_GEMM, 256, 0, stream>>>(h1, Wb1, b1, zs16, zn128);
    k_aggadd<128, true, false><<<NNODES / 4, 256, 0, stream>>>(zn128, zs16, row_ptr, edge_src, deg_inv, h2);
    // layer 2: h2 -> out (fp32), gather width 64
    k_gemm2<64, true><<<NBLK_GEMM, 256, 0, stream>>>(h2, Wb2, b2, zs32, zn64);
    k_aggadd<64, false, true><<<NNODES / 4, 256, 0, stream>>>(zn64, zs32, row_ptr, edge_src, deg_inv, out);
}

// Round 10
// 448.308 us; speedup vs baseline: 1.3924x; 1.0748x over previous
//
#include <hip/hip_runtime.h>
#include <hip/hip_fp16.h>

#define NNODES 100000
#define NPAD   100032            // 64*1563
#define NEDGES 1600000
#define NBLK_GEMM (NPAD / 64)    // 1563

#define BKT   512                // nodes per bucket
#define NBKT  ((NNODES + BKT - 1) / BKT)   // 196
#define CAP   10240              // real-edge slab capacity (mean 8192)
#define PCAP  18432              // padded slab capacity (CAP + 512*16)
#define EPB   2048               // edges per block, pass A
#define NBLK_A ((NEDGES + EPB - 1) / EPB)

typedef _Float16 half8 __attribute__((ext_vector_type(8)));
typedef float floatx4 __attribute__((ext_vector_type(4)));

// ---------------- CSR pass A (verbatim R6) ----------------

__global__ __launch_bounds__(256) void k_binA(const int* __restrict__ src, const int* __restrict__ dst,
                                              int* __restrict__ gcur, unsigned* __restrict__ pairs) {
    __shared__ int cnt[NBKT];
    __shared__ int cur[NBKT];
    int t = threadIdx.x;
    if (t < NBKT) cnt[t] = 0;
    __syncthreads();
    int e0 = blockIdx.x * EPB;
    for (int i = t; i < EPB; i += 256) {
        int e = e0 + i;
        if (e < NEDGES) atomicAdd(&cnt[dst[e] >> 9], 1);
    }
    __syncthreads();
    if (t < NBKT) {
        int c = cnt[t];
        cur[t] = (c > 0) ? atomicAdd(&gcur[t], c) : 0;
    }
    __syncthreads();
    for (int i = t; i < EPB; i += 256) {
        int e = e0 + i;
        if (e < NEDGES) {
            int d = dst[e];
            int b = d >> 9;
            int pos = atomicAdd(&cur[b], 1);
            pairs[b * CAP + pos] = (unsigned)src[e] | ((unsigned)(d & 511) << 20);
        }
    }
}

// ---------------- CSR pass B with 16-padding ----------------
// per-bucket slab of PCAP edge slots at base b*PCAP; each node's edges padded
// to a multiple of 16 with sentinel NNODES (a zeroed feature row).
__global__ __launch_bounds__(512) void k_binB(const unsigned* __restrict__ pairs,
                                              const int* __restrict__ gcnt,
                                              int* __restrict__ row_beg, int* __restrict__ row_end,
                                              float* __restrict__ deg_inv,
                                              int* __restrict__ edge_src) {
    __shared__ int hist[BKT];
    __shared__ int sc[BKT];
    int b = blockIdx.x;
    int t = threadIdx.x;
    int n = gcnt[b];
    int base = b * PCAP;
    const unsigned* pp = pairs + (size_t)b * CAP;
    hist[t] = 0;
    __syncthreads();
    for (int i = t; i < n; i += 512) atomicAdd(&hist[pp[i] >> 20], 1);
    __syncthreads();
    int v = hist[t];                       // real degree of node b*512+t
    int pdeg = (v + 15) & ~15;             // padded to multiple of 16
    sc[t] = pdeg;
    __syncthreads();
#pragma unroll
    for (int off = 1; off < 512; off <<= 1) {
        int u = (t >= off) ? sc[t - off] : 0;
        __syncthreads();
        sc[t] += u;
        __syncthreads();
    }
    int pref = sc[t] - pdeg;               // exclusive prefix of padded degs
    int node = b * BKT + t;
    if (node < NNODES) {
        row_beg[node] = base + pref;
        row_end[node] = base + pref + pdeg;
        deg_inv[node] = 1.0f / fmaxf((float)v, 1.0f);
    }
    // sentinel-fill the padding slots
    for (int i = v; i < pdeg; ++i) edge_src[base + pref + i] = NNODES;
    __syncthreads();
    hist[t] = pref;                        // hist -> scatter cursor
    __syncthreads();
    for (int i = t; i < n; i += 512) {
        unsigned p = pp[i];
        int pos = atomicAdd(&hist[p >> 20], 1);
        edge_src[base + pos] = (int)(p & 0xFFFFF);
    }
}

// ---------------- fused prep: f2h + 3x wshuf (verbatim R6) -------------------
template <int C>
__device__ inline void wshuf_one(const float* __restrict__ Ws, const float* __restrict__ Wn,
                                 __half* __restrict__ Wb, int t) {
    constexpr int NCT = 2 * C / 16;
    int lane  = t & 63;
    int ctile = (t >> 6) % NCT;
    int kstep = t / (64 * NCT);
    int n  = ctile * 16 + (lane & 15);
    int k0 = kstep * 32 + (lane >> 4) * 8;
    half8 w8;
#pragma unroll
    for (int j = 0; j < 8; ++j) {
        int k = k0 + j;
        float w = (n < C) ? Ws[k * C + n] : Wn[k * C + (n - C)];
        w8[j] = (_Float16)w;
    }
    ((half8*)Wb)[t] = w8;
}

#define F2H_BLK 12500   // NNODES*128 floats = 3.2M float4 / 256

__global__ __launch_bounds__(256) void k_prep(const float* __restrict__ x, __half* __restrict__ x16,
                                              const float* __restrict__ Ws0, const float* __restrict__ Wn0, __half* __restrict__ Wb0,
                                              const float* __restrict__ Ws1, const float* __restrict__ Wn1, __half* __restrict__ Wb1,
                                              const float* __restrict__ Ws2, const float* __restrict__ Wn2, __half* __restrict__ Wb2) {
    int blk = blockIdx.x;
    if (blk < F2H_BLK) {
        int i = blk * 256 + threadIdx.x;
        float4 v = ((const float4*)x)[i];
        __half2* o = (__half2*)(x16 + (size_t)i * 4);
        o[0] = __floats2half2_rn(v.x, v.y);
        o[1] = __floats2half2_rn(v.z, v.w);
    } else if (blk < F2H_BLK + 16) {
        wshuf_one<128>(Ws0, Wn0, Wb0, (blk - F2H_BLK) * 256 + threadIdx.x);
    } else if (blk < F2H_BLK + 32) {
        wshuf_one<128>(Ws1, Wn1, Wb1, (blk - F2H_BLK - 16) * 256 + threadIdx.x);
    } else {
        wshuf_one<64>(Ws2, Wn2, Wb2, (blk - F2H_BLK - 32) * 256 + threadIdx.x);
    }
}

// ---------------- MFMA GEMM (R6 + zeroed zn sentinel row) --------------------
template <int C, bool ZS32>
__global__ __launch_bounds__(256) void k_gemm2(const __half* __restrict__ A,
                                               const __half* __restrict__ Wb,
                                               const float* __restrict__ bias,
                                               void* __restrict__ zs,
                                               __half* __restrict__ zn) {
    constexpr int NCT = 2 * C / 16;
    int lane = threadIdx.x & 63;
    int wave = threadIdx.x >> 6;
    int row0 = blockIdx.x * 64 + wave * 16;
    int m = lane & 15, quad = lane >> 4;
    const half8* Aq = (const half8*)(A + (size_t)(row0 + m) * 128 + quad * 8);
    const half8* Bq = (const half8*)Wb;

    floatx4 acc[NCT];
#pragma unroll
    for (int c = 0; c < NCT; ++c) acc[c] = floatx4{0.f, 0.f, 0.f, 0.f};

#pragma unroll
    for (int ks = 0; ks < 4; ++ks) {
        half8 a = Aq[ks * 4];
#pragma unroll
        for (int c = 0; c < NCT; ++c) {
            half8 b = Bq[(size_t)(ks * NCT + c) * 64 + lane];
            acc[c] = __builtin_amdgcn_mfma_f32_16x16x32_f16(a, b, acc[c], 0, 0, 0);
        }
    }

#pragma unroll
    for (int c = 0; c < NCT; ++c) {
        bool is_self = (c < NCT / 2);
        int col = (is_self ? c : c - NCT / 2) * 16 + m;
        float bv = is_self ? bias[col] : 0.f;
#pragma unroll
        for (int r = 0; r < 4; ++r) {
            int row = row0 + quad * 4 + r;
            float v = acc[c][r] + bv;
            if (is_self) {
                if (row < NNODES) {
                    if (ZS32) ((float*)zs)[(size_t)row * C + col] = v;
                    else      ((__half*)zs)[(size_t)row * C + col] = __float2half(v);
                }
            } else {
                // zn gets a zeroed sentinel row at index NNODES (gather padding)
                if (row < NNODES)       zn[(size_t)row * C + col] = __float2half(v);
                else if (row == NNODES) zn[(size_t)row * C + col] = __float2half(0.f);
            }
        }
    }
}

// ---------------- gather-add, batch-only (padded CSR) ------------------------
// Every node's edge count is a multiple of 16 = NSUB*UNR, so the batch loop is
// exact: all 16 loads of a batch are independent and in flight together.
template <int C, bool RELU, bool ZS32>
__global__ __launch_bounds__(256) void k_aggadd(const __half* __restrict__ zn,
                                                const void* __restrict__ zs,
                                                const int* __restrict__ row_beg,
                                                const int* __restrict__ row_end,
                                                const int* __restrict__ edge_src,
                                                const float* __restrict__ deg_inv,
                                                void* __restrict__ outv) {
    constexpr int LPR  = C / 8;            // half8 chunks per row (16 or 8)
    constexpr int NSUB = 64 / LPR;         // 4 (C=128) or 8 (C=64)
    constexpr int UNR  = 16 / NSUB;        // 4 or 2 -> batch = 16 edges
    int node = blockIdx.x * 4 + (threadIdx.x >> 6);
    int lane = threadIdx.x & 63;
    int su = lane / LPR;
    int lr = lane % LPR;
    int beg = row_beg[node];
    int end = row_end[node];
    const half8* zb = (const half8*)zn;
    float a[UNR][8];
#pragma unroll
    for (int u = 0; u < UNR; ++u)
#pragma unroll
        for (int j = 0; j < 8; ++j) a[u][j] = 0.f;

    for (int p = beg + su; p + NSUB * (UNR - 1) < end; p += NSUB * UNR) {
        half8 v[UNR];
#pragma unroll
        for (int u = 0; u < UNR; ++u) v[u] = zb[(size_t)edge_src[p + u * NSUB] * LPR + lr];
#pragma unroll
        for (int u = 0; u < UNR; ++u)
#pragma unroll
            for (int j = 0; j < 8; ++j) a[u][j] = fmaf((float)v[u][j], 1.0f, a[u][j]);
    }

    float s[8];
#pragma unroll
    for (int j = 0; j < 8; ++j) {
        s[j] = a[0][j];
#pragma unroll
        for (int u = 1; u < UNR; ++u) s[j] += a[u][j];
    }
#pragma unroll
    for (int off = 32; off >= LPR; off >>= 1) {
#pragma unroll
        for (int j = 0; j < 8; ++j) s[j] += __shfl_xor(s[j], off, 64);
    }

    if (su == 0) {
        float di = deg_inv[node];
        float o[8];
        if (ZS32) {
            const float4* zp = (const float4*)zs + (size_t)node * (C / 4) + lr * 2;
            float4 z0 = zp[0], z1 = zp[1];
            o[0] = z0.x + s[0] * di; o[1] = z0.y + s[1] * di;
            o[2] = z0.z + s[2] * di; o[3] = z0.w + s[3] * di;
            o[4] = z1.x + s[4] * di; o[5] = z1.y + s[5] * di;
            o[6] = z1.z + s[6] * di; o[7] = z1.w + s[7] * di;
        } else {
            half8 z = ((const half8*)zs)[(size_t)node * LPR + lr];
#pragma unroll
            for (int j = 0; j < 8; ++j) o[j] = (float)z[j] + s[j] * di;
        }
        if (RELU) {
#pragma unroll
            for (int j = 0; j < 8; ++j) o[j] = fmaxf(o[j], 0.f);
        }
        if (ZS32) {
            float4* op = (float4*)outv + (size_t)node * (C / 4) + lr * 2;
            op[0] = float4{o[0], o[1], o[2], o[3]};
            op[1] = float4{o[4], o[5], o[6], o[7]};
        } else {
            half8 h;
#pragma unroll
            for (int j = 0; j < 8; ++j) h[j] = (_Float16)o[j];
            ((half8*)outv)[(size_t)node * LPR + lr] = h;
        }
    }
}

// ---------------- launch ----------------

extern "C" void kernel_launch(void* const* d_in, const int* in_sizes, int n_in,
                              void* d_out, int out_size, void* d_ws, size_t ws_size,
                              hipStream_t stream) {
    const float* x   = (const float*)d_in[0];
    const int*   src = (const int*)d_in[1];
    const int*   dst = (const int*)d_in[2];
    const float* Ws0 = (const float*)d_in[3];
    const float* Wn0 = (const float*)d_in[4];
    const float* b0  = (const float*)d_in[5];
    const float* Ws1 = (const float*)d_in[6];
    const float* Wn1 = (const float*)d_in[7];
    const float* b1  = (const float*)d_in[8];
    const float* Ws2 = (const float*)d_in[9];
    const float* Wn2 = (const float*)d_in[10];
    const float* b2  = (const float*)d_in[11];
    float* out = (float*)d_out;

    char* ws = (char*)d_ws;
    size_t off = 0;
    auto alloc = [&](size_t bytes) -> void* {
        off = (off + 255) & ~(size_t)255;
        void* p = ws + off;
        off += bytes;
        return p;
    };
    int*      row_beg  = (int*)alloc((size_t)NNODES * 4);
    int*      row_end  = (int*)alloc((size_t)NNODES * 4);
    float*    deg_inv  = (float*)alloc((size_t)NNODES * 4);
    int*      edge_src = (int*)alloc((size_t)NBKT * PCAP * 4);
    int*      gcur     = (int*)alloc((size_t)NBKT * 4);
    unsigned* pairs    = (unsigned*)alloc((size_t)NBKT * CAP * 4);
    __half*   x16      = (__half*)alloc((size_t)NPAD * 128 * 2);
    __half*   h1       = (__half*)alloc((size_t)NPAD * 128 * 2);
    __half*   h2       = (__half*)alloc((size_t)NPAD * 128 * 2);
    __half*   zs16     = (__half*)alloc((size_t)NNODES * 128 * 2);
    __half*   zn128    = (__half*)alloc((size_t)NPAD * 128 * 2);
    float*    zs32     = (float*)alloc((size_t)NNODES * 64 * 4);
    __half*   zn64     = (__half*)alloc((size_t)NPAD * 64 * 2);
    __half*   Wb0      = (__half*)alloc((size_t)4 * 16 * 64 * 8 * 2);
    __half*   Wb1      = (__half*)alloc((size_t)4 * 16 * 64 * 8 * 2);
    __half*   Wb2      = (__half*)alloc((size_t)4 * 8 * 64 * 8 * 2);
    (void)ws_size; (void)n_in; (void)in_sizes; (void)out_size;

    // CSR build (bucketed, padded)
    hipMemsetAsync(gcur, 0, (size_t)NBKT * 4, stream);
    k_binA<<<NBLK_A, 256, 0, stream>>>(src, dst, gcur, pairs);
    k_binB<<<NBKT, 512, 0, stream>>>(pairs, gcur, row_beg, row_end, deg_inv, edge_src);

    // prep: f2h + 3x wshuf fused
    k_prep<<<F2H_BLK + 40, 256, 0, stream>>>(x, x16, Ws0, Wn0, Wb0, Ws1, Wn1, Wb1, Ws2, Wn2, Wb2);

    // layer 0: x16 -> h1
    k_gemm2<128, false><<<NBLK_GEMM, 256, 0, stream>>>(x16, Wb0, b0, zs16, zn128);
    k_aggadd<128, true, false><<<NNODES / 4, 256, 0, stream>>>(zn128, zs16, row_beg, row_end, edge_src, deg_inv, h1);
    // layer 1: h1 -> h2
    k_gemm2<128, false><<<NBLK_GEMM, 256, 0, stream>>>(h1, Wb1, b1, zs16, zn128);
    k_aggadd<128, true, false><<<NNODES / 4, 256, 0, stream>>>(zn128, zs16, row_beg, row_end, edge_src, deg_inv, h2);
    // layer 2: h2 -> out (fp32), gather width 64
    k_gemm2<64, true><<<NBLK_GEMM, 256, 0, stream>>>(h2, Wb2, b2, zs32, zn64);
    k_aggadd<64, false, true><<<NNODES / 4, 256, 0, stream>>>(zn64, zs32, row_beg, row_end, edge_src, deg_inv, out);
}